// Round 8
// baseline (283.996 us; speedup 1.0000x reference)
//
#include <hip/hip_runtime.h>
#include <hip/hip_bf16.h>

// N=2 batch, S=2048 seq, M=1024 d_model, H=16 heads, D=64 head dim
#define NB 2
#define SEQ 2048
#define DM 1024
#define NH 16
#define HD 64

typedef unsigned short u16;
typedef unsigned int u32;
typedef __attribute__((ext_vector_type(8))) short bf16x8;
typedef __attribute__((ext_vector_type(4))) float f32x4;
typedef __attribute__((ext_vector_type(4))) unsigned short u16x4;
typedef __attribute__((ext_vector_type(2))) unsigned int u32x2;

#define MFMA __builtin_amdgcn_mfma_f32_16x16x32_bf16

// log2(e) * 0.125  (attention scale folded with exp2 conversion)
#define QSCALE 0.18033688011112042f

__device__ __forceinline__ u16 bf16_rne(float x) {
    unsigned int u = __float_as_uint(x);
    return (u16)((u + 0x7FFFu + ((u >> 16) & 1u)) >> 16);
}
__device__ __forceinline__ float bf16f(u16 h) {
    return __uint_as_float(((unsigned int)h) << 16);
}
__device__ __forceinline__ void split2(float x, u16& h, u16& l) {
    h = bf16_rne(x);
    l = bf16_rne(x - bf16f(h));
}
// packed 2xf32 -> 2xbf16 (RNE), one instruction
__device__ __forceinline__ u32 cvt_pk_bf16(float lo, float hi) {
    u32 r;
    asm("v_cvt_pk_bf16_f32 %0, %1, %2" : "=v"(r) : "v"(lo), "v"(hi));
    return r;
}
// 2^x on the transcendental pipe
__device__ __forceinline__ float exp2_fast(float x) {
#if __has_builtin(__builtin_amdgcn_exp2f)
    return __builtin_amdgcn_exp2f(x);
#else
    float r;
    asm("v_exp_f32 %0, %1" : "=v"(r) : "v"(x));
    return r;
#endif
}

// async global->LDS, 16B per lane. LDS dest = wave-uniform base + lane*16.
__device__ __forceinline__ void async16(const u16* g, u16* l) {
    typedef const __attribute__((address_space(1))) u32* GP;
    typedef __attribute__((address_space(3))) u32* LP;
    __builtin_amdgcn_global_load_lds((GP)g, (LP)l, 16, 0, 0);
}

// ---------------------------------------------------------------------------
// Pre-split pass (unchanged from round 7).
// ---------------------------------------------------------------------------
__global__ __launch_bounds__(256) void presplit(
    const float* __restrict__ x0, const float* __restrict__ x1,
    const float* __restrict__ x2, const float* __restrict__ wq,
    const float* __restrict__ wk, const float* __restrict__ wv,
    const float* __restrict__ wo,
    u16* __restrict__ xh, u16* __restrict__ wh, u16* __restrict__ wl)
{
    const int seg = blockIdx.y;
    const float* src;
    u16* dh;
    u16* dl = nullptr;
    int n4;
    float sc = 1.f;
    if (seg < 3) {
        src = (seg == 0) ? x0 : (seg == 1) ? x1 : x2;
        dh = xh + (size_t)seg * 4194304;
        n4 = 1048576;
    } else {
        int s2 = seg - 3;
        src = (s2 == 0) ? wq : (s2 == 1) ? wk : (s2 == 2) ? wv : wo;
        dh = wh + (size_t)s2 * 1048576;
        if (s2 == 3) dl = wl + (size_t)s2 * 1048576;   // Wo lo
        n4 = 262144;
        if (s2 == 0) sc = QSCALE;
    }
    for (int i = blockIdx.x * 256 + threadIdx.x; i < n4; i += gridDim.x * 256) {
        float4 v = ((const float4*)src)[i];
        v.x *= sc; v.y *= sc; v.z *= sc; v.w *= sc;
        u16 h0 = bf16_rne(v.x), h1 = bf16_rne(v.y);
        u16 h2 = bf16_rne(v.z), h3 = bf16_rne(v.w);
        u16x4 hv = {h0, h1, h2, h3};
        *(u16x4*)(dh + (size_t)i * 4) = hv;
        if (dl) {
            u16x4 lv = {bf16_rne(v.x - bf16f(h0)), bf16_rne(v.y - bf16f(h1)),
                        bf16_rne(v.z - bf16f(h2)), bf16_rne(v.w - bf16f(h3))};
            *(u16x4*)(dl + (size_t)i * 4) = lv;
        }
    }
}

// ---------------------------------------------------------------------------
// QKV GEMM, plain bf16, BK=64 (unchanged from round 7).
// ---------------------------------------------------------------------------
__global__ __launch_bounds__(256, 4) void gemm_qkv(
    const u16* __restrict__ xh3, const u16* __restrict__ wh3,
    const float* __restrict__ bq, const float* __restrict__ bk,
    const float* __restrict__ bv,
    u16* qh, u16* ql, u16* kh, u16* vth)
{
    __shared__ u16 A0[128][32], A1[128][32], B0[128][32], B1[128][32];

    const int tid = threadIdx.x, lane = tid & 63, w = tid >> 6;
    const int lg = lane >> 4, lc = lane & 15;

    const int id = blockIdx.x + 8 * blockIdx.y;
    const int swz = (id & 7) * 32 + (id >> 3);
    const int c0 = (swz & 7) * 128, r0 = (swz >> 3) * 128;

    const int z = blockIdx.z;
    const u16* ag = xh3 + (size_t)z * 4194304;
    const u16* bg = wh3 + (size_t)z * 1048576;
    const float* bias = (z == 0) ? bq : (z == 1) ? bk : bv;

    const u16* gb = (w < 2) ? ag : bg;
    u16* lb = (w == 0) ? &A0[0][0] : (w == 1) ? &A1[0][0]
            : (w == 2) ? &B0[0][0] : &B1[0][0];
    const int rbase = (w < 2) ? r0 : c0;
    const int colofs = (w & 1) * 32;
    const u16* gsrc0 = gb + (size_t)(rbase + (lane >> 2)) * DM + colofs + (lane & 3) * 8;

    const int wr = (w >> 1) * 64, wc = (w & 1) * 64;

    f32x4 acc[4][4];
#pragma unroll
    for (int i = 0; i < 4; ++i)
#pragma unroll
        for (int j = 0; j < 4; ++j) acc[i][j] = (f32x4)0.f;

    for (int ks = 0; ks < DM; ks += 64) {
        __syncthreads();
#pragma unroll
        for (int i = 0; i < 8; ++i)
            async16(gsrc0 + (size_t)i * 16 * DM + ks, lb + i * 512);
        __syncthreads();

#pragma unroll
        for (int kk = 0; kk < 2; ++kk) {
            const u16(*Ak)[32] = kk ? A1 : A0;
            const u16(*Bk)[32] = kk ? B1 : B0;
            bf16x8 ah[4], bh[4];
#pragma unroll
            for (int rt = 0; rt < 4; ++rt)
                ah[rt] = *(const bf16x8*)&Ak[wr + rt * 16 + lc][lg * 8];
#pragma unroll
            for (int jt = 0; jt < 4; ++jt)
                bh[jt] = *(const bf16x8*)&Bk[wc + jt * 16 + lc][lg * 8];
#pragma unroll
            for (int jt = 0; jt < 4; ++jt)
#pragma unroll
                for (int rt = 0; rt < 4; ++rt)
                    acc[rt][jt] = MFMA(ah[rt], bh[jt], acc[rt][jt], 0, 0, 0);
        }
    }

#pragma unroll
    for (int rt = 0; rt < 4; ++rt)
#pragma unroll
        for (int jt = 0; jt < 4; ++jt)
#pragma unroll
            for (int r = 0; r < 4; ++r) {
                int row = r0 + wr + rt * 16 + lg * 4 + r;
                int col = c0 + wc + jt * 16 + lc;
                int h = col >> 6, d = col & 63, n = row >> 11, s = row & 2047;
                if (z == 0) {
                    float v = acc[rt][jt][r] + bias[col] * QSCALE;
                    size_t idx = ((size_t)((h << 1) | n) * SEQ + s) * HD + d;
                    u16 hh, ll; split2(v, hh, ll);
                    qh[idx] = hh; ql[idx] = ll;
                } else if (z == 1) {
                    float v = acc[rt][jt][r] + bias[col];
                    size_t idx = ((size_t)((h << 1) | n) * SEQ + s) * HD + d;
                    kh[idx] = bf16_rne(v);
                } else {
                    float v = acc[rt][jt][r] + bias[col];
                    size_t idx = ((size_t)((h << 1) | n) * HD + d) * SEQ + s;
                    vth[idx] = bf16_rne(v);
                }
            }
}

// ---------------------------------------------------------------------------
// Final projection GEMM, 3-term split (unchanged from round 7).
// ---------------------------------------------------------------------------
__global__ __launch_bounds__(256, 2) void gemm_proj(
    const u16* __restrict__ yh, const u16* __restrict__ yl,
    const u16* __restrict__ woh, const u16* __restrict__ wol,
    const float* __restrict__ bo, float* __restrict__ outf)
{
    __shared__ u16 Ah[128][32], Al[128][32], Bh[128][32], Bl[128][32];

    const int tid = threadIdx.x, lane = tid & 63, w = tid >> 6;
    const int lg = lane >> 4, lc = lane & 15;

    const int id = blockIdx.x + 8 * blockIdx.y;
    const int swz = (id & 7) * 32 + (id >> 3);
    const int c0 = (swz & 7) * 128, r0 = (swz >> 3) * 128;

    const u16* gb = (w == 0) ? yh : (w == 1) ? yl : (w == 2) ? woh : wol;
    u16* lb = (w == 0) ? &Ah[0][0] : (w == 1) ? &Al[0][0] : (w == 2) ? &Bh[0][0] : &Bl[0][0];
    const int rbase = (w < 2) ? r0 : c0;
    const u16* gsrc0 = gb + (size_t)(rbase + (lane >> 2)) * DM + (lane & 3) * 8;

    const int wr = (w >> 1) * 64, wc = (w & 1) * 64;

    f32x4 acc[4][4];
#pragma unroll
    for (int i = 0; i < 4; ++i)
#pragma unroll
        for (int j = 0; j < 4; ++j) acc[i][j] = (f32x4)0.f;

    for (int ks = 0; ks < DM; ks += 32) {
        __syncthreads();
#pragma unroll
        for (int i = 0; i < 8; ++i)
            async16(gsrc0 + (size_t)i * 16 * DM + ks, lb + i * 512);
        __syncthreads();

        bf16x8 ah[4], al[4];
#pragma unroll
        for (int rt = 0; rt < 4; ++rt) {
            ah[rt] = *(const bf16x8*)&Ah[wr + rt * 16 + lc][lg * 8];
            al[rt] = *(const bf16x8*)&Al[wr + rt * 16 + lc][lg * 8];
        }
#pragma unroll
        for (int jt = 0; jt < 4; ++jt) {
            bf16x8 bh2 = *(const bf16x8*)&Bh[wc + jt * 16 + lc][lg * 8];
            bf16x8 bl2 = *(const bf16x8*)&Bl[wc + jt * 16 + lc][lg * 8];
#pragma unroll
            for (int rt = 0; rt < 4; ++rt) {
                acc[rt][jt] = MFMA(ah[rt], bh2, acc[rt][jt], 0, 0, 0);
                acc[rt][jt] = MFMA(ah[rt], bl2, acc[rt][jt], 0, 0, 0);
                acc[rt][jt] = MFMA(al[rt], bh2, acc[rt][jt], 0, 0, 0);
            }
        }
    }

#pragma unroll
    for (int rt = 0; rt < 4; ++rt)
#pragma unroll
        for (int jt = 0; jt < 4; ++jt)
#pragma unroll
            for (int r = 0; r < 4; ++r) {
                int row = r0 + wr + rt * 16 + lg * 4 + r;
                int col = c0 + wc + jt * 16 + lc;
                outf[(size_t)row * DM + col] = acc[rt][jt][r] + bo[col];
            }
}

// ---------------------------------------------------------------------------
// Flash attention v3: QBLK=64 (wave=16 q-rows), grid 1024 (4 blocks/CU),
// double-buffered K/V staged by global_load_lds with inverse-swizzled
// SOURCE + swizzled READ (granule g -> g^(row&7) within each 128B row;
// rule-21 both-sides involution), Pb same XOR (no padding anywhere:
// LDS = 32KB K/V dbuf + 8KB Pb = 40960B exactly -> 4 blocks/CU).
// T3-lite schedule: issue next-tile DMA before compute, one
// vmcnt(0)+barrier per tile. Swapped-operand softmax as proven.
// ---------------------------------------------------------------------------
__global__ __launch_bounds__(256, 4) void attn_k(
    const u16* __restrict__ qh, const u16* __restrict__ ql,
    const u16* __restrict__ kh, const u16* __restrict__ vth,
    u16* __restrict__ yh, u16* __restrict__ yl)
{
    __shared__ u16 Ks[2][64][64], Vs[2][64][64];
    __shared__ u16 Pb[4][16][64];

    const int tid = threadIdx.x, lane = tid & 63, w = tid >> 6;
    const int lg = lane >> 4, lc = lane & 15;

    // bijective XCD-chunk swizzle over 1024 blocks (1024 % 8 == 0):
    // XCD x serves widx [x*128, x*128+128) = 4 consecutive hn values.
    const int id = blockIdx.x + 32 * blockIdx.y;
    const int widx = (id & 7) * 128 + (id >> 3);
    const int hn = widx >> 5;
    const int qb0 = (widx & 31) * 64;

    const size_t qkbase = (size_t)hn * SEQ * HD;
    const size_t vbase = (size_t)hn * HD * SEQ;

    // staging geometry: chunk c (of 8) = 1KB = rows c*8..c*8+7 of a [64][64]
    // u16 tile; lane l covers row c*8+(l>>3), granule (l&7); source granule
    // pre-swizzled g' = (l&7) ^ ((l>>3)&7)  (row&7 == (l>>3)&7 since c*8%8==0)
    const int srow = lane >> 3;                       // row within chunk
    const int sg = (lane & 7) ^ (srow & 7);           // source granule

#define STAGE_KV(buf, kt0)                                                   \
    {                                                                        \
        _Pragma("unroll")                                                    \
        for (int cc = 0; cc < 2; ++cc) {                                     \
            const int c = w * 2 + cc;                                        \
            const int r = c * 8 + srow;                                      \
            async16(kh + qkbase + (size_t)((kt0) + r) * HD + sg * 8,         \
                    &Ks[buf][0][0] + c * 512);                               \
            async16(vth + vbase + (size_t)r * SEQ + (kt0) + sg * 8,          \
                    &Vs[buf][0][0] + c * 512);                               \
        }                                                                    \
    }

    // Q fragments (hi/lo) — B-operand; 16 q-rows per wave
    bf16x8 qfh[2], qfl[2];
#pragma unroll
    for (int kc = 0; kc < 2; ++kc) {
        size_t off = qkbase + (size_t)(qb0 + w * 16 + lc) * HD + kc * 32 + lg * 8;
        qfh[kc] = *(const bf16x8*)(qh + off);
        qfl[kc] = *(const bf16x8*)(ql + off);
    }

    // O^T accumulator [dt]: row = d = dt*16+lg*4+r, col = q = lc
    f32x4 ot[4];
#pragma unroll
    for (int j = 0; j < 4; ++j) ot[j] = (f32x4)0.f;
    float m_ = -3e38f, s_ = 0.f;

    STAGE_KV(0, 0);
    asm volatile("s_waitcnt vmcnt(0)" ::: "memory");
    __syncthreads();

    int cur = 0;
    for (int t = 0; t < SEQ / 64; ++t) {
        if (t < SEQ / 64 - 1) STAGE_KV(cur ^ 1, (t + 1) * 64);

        // ---- S^T = K·Q^T (2-term: k plain, q hi/lo): row=l, col=q=lc ----
        f32x4 st[4];
#pragma unroll
        for (int j = 0; j < 4; ++j) st[j] = (f32x4)0.f;
        __builtin_amdgcn_s_setprio(1);
#pragma unroll
        for (int jt = 0; jt < 4; ++jt)
#pragma unroll
            for (int kc = 0; kc < 2; ++kc) {
                bf16x8 k8 = *(const bf16x8*)
                    &Ks[cur][jt * 16 + lc][(((kc << 2) | lg) ^ (lc & 7)) * 8];
                st[jt] = MFMA(k8, qfh[kc], st[jt], 0, 0, 0);
                st[jt] = MFMA(k8, qfl[kc], st[jt], 0, 0, 0);
            }
        __builtin_amdgcn_s_setprio(0);

        // ---- softmax (per q=lc; scores in log2 units) ----
        {
            float t0 = fmaxf(fmaxf(st[0][0], st[0][1]), fmaxf(st[0][2], st[0][3]));
            float t1 = fmaxf(fmaxf(st[1][0], st[1][1]), fmaxf(st[1][2], st[1][3]));
            float t2 = fmaxf(fmaxf(st[2][0], st[2][1]), fmaxf(st[2][2], st[2][3]));
            float t3 = fmaxf(fmaxf(st[3][0], st[3][1]), fmaxf(st[3][2], st[3][3]));
            float tm = fmaxf(fmaxf(t0, t1), fmaxf(t2, t3));
            tm = fmaxf(tm, __shfl_xor(tm, 16));
            tm = fmaxf(tm, __shfl_xor(tm, 32));
            if (__any(tm - m_ > 8.0f)) {
                float mnew = fmaxf(m_, tm);
                float resc = exp2_fast(m_ - mnew);
                m_ = mnew;
                s_ *= resc;
#pragma unroll
                for (int dt = 0; dt < 4; ++dt) {
                    ot[dt][0] *= resc; ot[dt][1] *= resc;
                    ot[dt][2] *= resc; ot[dt][3] *= resc;
                }
            }
#pragma unroll
            for (int jt = 0; jt < 4; ++jt) {
                float p0 = exp2_fast(st[jt][0] - m_);
                float p1 = exp2_fast(st[jt][1] - m_);
                float p2 = exp2_fast(st[jt][2] - m_);
                float p3 = exp2_fast(st[jt][3] - m_);
                s_ += (p0 + p1) + (p2 + p3);
                u32x2 pk = {cvt_pk_bf16(p0, p1), cvt_pk_bf16(p2, p3)};
                // P[q=lc][l = jt*16+lg*4 ..+3], XOR-swizzled (element^(lc&7)<<3)
                *(u32x2*)&Pb[w][lc][(jt * 16 + lg * 4) ^ ((lc & 7) << 3)] = pk;
            }
        }

        // ---- O^T += V^T · P^T ----
        bf16x8 pb[2];
#pragma unroll
        for (int jc = 0; jc < 2; ++jc)
            pb[jc] = *(const bf16x8*)
                &Pb[w][lc][(jc * 32 + lg * 8) ^ ((lc & 7) << 3)];
        __builtin_amdgcn_s_setprio(1);
#pragma unroll
        for (int dt = 0; dt < 4; ++dt)
#pragma unroll
            for (int jc = 0; jc < 2; ++jc) {
                bf16x8 v8 = *(const bf16x8*)
                    &Vs[cur][dt * 16 + lc][(((jc << 2) | lg) ^ (lc & 7)) * 8];
                ot[dt] = MFMA(v8, pb[jc], ot[dt], 0, 0, 0);
            }
        __builtin_amdgcn_s_setprio(0);

        asm volatile("s_waitcnt vmcnt(0)" ::: "memory");
        __syncthreads();
        cur ^= 1;
    }

    // ---- epilogue ----
    const int h = hn >> 1, n = hn & 1;
    {
        float v = s_;
        v += __shfl_xor(v, 16);
        v += __shfl_xor(v, 32);
        s_ = 1.f / v;
    }
    const int qrow = qb0 + w * 16 + lc;
    size_t rowoff = (size_t)(n * SEQ + qrow) * DM + h * HD;
#pragma unroll
    for (int dt = 0; dt < 4; ++dt) {
        u16x4 hv, lv;
#pragma unroll
        for (int r = 0; r < 4; ++r) {
            float y = ot[dt][r] * s_;
            u16 hh, ll; split2(y, hh, ll);
            hv[r] = hh; lv[r] = ll;
        }
        size_t idx = rowoff + dt * 16 + lg * 4;
        *(u16x4*)(yh + idx) = hv;
        *(u16x4*)(yl + idx) = lv;
    }
#undef STAGE_KV
}

// ---------------------------------------------------------------------------
extern "C" void kernel_launch(void* const* d_in, const int* in_sizes, int n_in,
                              void* d_out, int out_size, void* d_ws, size_t ws_size,
                              hipStream_t stream)
{
    const float* query = (const float*)d_in[0];
    const float* key_  = (const float*)d_in[1];
    const float* value = (const float*)d_in[2];
    const float* Wq = (const float*)d_in[3];
    const float* bq = (const float*)d_in[4];
    const float* Wk = (const float*)d_in[5];
    const float* bk = (const float*)d_in[6];
    const float* Wv = (const float*)d_in[7];
    const float* bv = (const float*)d_in[8];
    const float* Wo = (const float*)d_in[9];
    const float* bo = (const float*)d_in[10];
    float* out = (float*)d_out;

    char* p = (char*)d_ws;
    u16* wh  = (u16*)(p);
    u16* wl  = (u16*)(p + 8388608ull);
    u16* qh  = (u16*)(p + 16777216ull);
    u16* ql  = (u16*)(p + 25165824ull);
    u16* kh  = (u16*)(p + 33554432ull);
    u16* vth = (u16*)(p + 50331648ull);
    u16* xh  = (u16*)(p + 67108864ull);
    u16* yh  = (u16*)(p + 67108864ull);
    u16* yl  = (u16*)(p + 75497472ull);

    presplit<<<dim3(256, 7), 256, 0, stream>>>(
        query, key_, value, Wq, Wk, Wv, Wo, xh, wh, wl);

    gemm_qkv<<<dim3(8, 32, 3), 256, 0, stream>>>(
        xh, wh, bq, bk, bv, qh, ql, kh, vth);

    attn_k<<<dim3(32, 32), 256, 0, stream>>>(qh, ql, kh, vth, yh, yl);

    gemm_proj<<<dim3(8, 32), 256, 0, stream>>>(
        yh, yl, wh + 3145728ull, wl + 3145728ull, bo, out);
}

// Round 10
// 271.528 us; speedup vs baseline: 1.0459x; 1.0459x over previous
//
#include <hip/hip_runtime.h>
#include <hip/hip_bf16.h>

// N=2 batch, S=2048 seq, M=1024 d_model, H=16 heads, D=64 head dim
#define NB 2
#define SEQ 2048
#define DM 1024
#define NH 16
#define HD 64

typedef unsigned short u16;
typedef unsigned int u32;
typedef __attribute__((ext_vector_type(8))) short bf16x8;
typedef __attribute__((ext_vector_type(4))) float f32x4;
typedef __attribute__((ext_vector_type(4))) unsigned short u16x4;
typedef __attribute__((ext_vector_type(2))) unsigned int u32x2;

#define MFMA __builtin_amdgcn_mfma_f32_16x16x32_bf16

// log2(e) * 0.125  (attention scale folded with exp2 conversion)
#define QSCALE 0.18033688011112042f

__device__ __forceinline__ u16 bf16_rne(float x) {
    unsigned int u = __float_as_uint(x);
    return (u16)((u + 0x7FFFu + ((u >> 16) & 1u)) >> 16);
}
__device__ __forceinline__ float bf16f(u16 h) {
    return __uint_as_float(((unsigned int)h) << 16);
}
__device__ __forceinline__ void split2(float x, u16& h, u16& l) {
    h = bf16_rne(x);
    l = bf16_rne(x - bf16f(h));
}
// packed 2xf32 -> 2xbf16 (RNE), one instruction
__device__ __forceinline__ u32 cvt_pk_bf16(float lo, float hi) {
    u32 r;
    asm("v_cvt_pk_bf16_f32 %0, %1, %2" : "=v"(r) : "v"(lo), "v"(hi));
    return r;
}
// 2^x on the transcendental pipe
__device__ __forceinline__ float exp2_fast(float x) {
#if __has_builtin(__builtin_amdgcn_exp2f)
    return __builtin_amdgcn_exp2f(x);
#else
    float r;
    asm("v_exp_f32 %0, %1" : "=v"(r) : "v"(x));
    return r;
#endif
}

// async global->LDS, 16B per lane. LDS dest = wave-uniform base + lane*16.
__device__ __forceinline__ void async16(const u16* g, u16* l) {
    typedef const __attribute__((address_space(1))) u32* GP;
    typedef __attribute__((address_space(3))) u32* LP;
    __builtin_amdgcn_global_load_lds((GP)g, (LP)l, 16, 0, 0);
}

// ---------------------------------------------------------------------------
// Pre-split pass (unchanged).
// ---------------------------------------------------------------------------
__global__ __launch_bounds__(256) void presplit(
    const float* __restrict__ x0, const float* __restrict__ x1,
    const float* __restrict__ x2, const float* __restrict__ wq,
    const float* __restrict__ wk, const float* __restrict__ wv,
    const float* __restrict__ wo,
    u16* __restrict__ xh, u16* __restrict__ wh, u16* __restrict__ wl)
{
    const int seg = blockIdx.y;
    const float* src;
    u16* dh;
    u16* dl = nullptr;
    int n4;
    float sc = 1.f;
    if (seg < 3) {
        src = (seg == 0) ? x0 : (seg == 1) ? x1 : x2;
        dh = xh + (size_t)seg * 4194304;
        n4 = 1048576;
    } else {
        int s2 = seg - 3;
        src = (s2 == 0) ? wq : (s2 == 1) ? wk : (s2 == 2) ? wv : wo;
        dh = wh + (size_t)s2 * 1048576;
        if (s2 == 3) dl = wl + (size_t)s2 * 1048576;   // Wo lo
        n4 = 262144;
        if (s2 == 0) sc = QSCALE;
    }
    for (int i = blockIdx.x * 256 + threadIdx.x; i < n4; i += gridDim.x * 256) {
        float4 v = ((const float4*)src)[i];
        v.x *= sc; v.y *= sc; v.z *= sc; v.w *= sc;
        u16 h0 = bf16_rne(v.x), h1 = bf16_rne(v.y);
        u16 h2 = bf16_rne(v.z), h3 = bf16_rne(v.w);
        u16x4 hv = {h0, h1, h2, h3};
        *(u16x4*)(dh + (size_t)i * 4) = hv;
        if (dl) {
            u16x4 lv = {bf16_rne(v.x - bf16f(h0)), bf16_rne(v.y - bf16f(h1)),
                        bf16_rne(v.z - bf16f(h2)), bf16_rne(v.w - bf16f(h3))};
            *(u16x4*)(dl + (size_t)i * 4) = lv;
        }
    }
}

// ---------------------------------------------------------------------------
// QKV GEMM, plain bf16, BK=64 (unchanged from round 9 — Q plain bf16).
// ---------------------------------------------------------------------------
__global__ __launch_bounds__(256, 4) void gemm_qkv(
    const u16* __restrict__ xh3, const u16* __restrict__ wh3,
    const float* __restrict__ bq, const float* __restrict__ bk,
    const float* __restrict__ bv,
    u16* qh, u16* kh, u16* vth)
{
    __shared__ u16 A0[128][32], A1[128][32], B0[128][32], B1[128][32];

    const int tid = threadIdx.x, lane = tid & 63, w = tid >> 6;
    const int lg = lane >> 4, lc = lane & 15;

    const int id = blockIdx.x + 8 * blockIdx.y;
    const int swz = (id & 7) * 32 + (id >> 3);
    const int c0 = (swz & 7) * 128, r0 = (swz >> 3) * 128;

    const int z = blockIdx.z;
    const u16* ag = xh3 + (size_t)z * 4194304;
    const u16* bg = wh3 + (size_t)z * 1048576;
    const float* bias = (z == 0) ? bq : (z == 1) ? bk : bv;

    const u16* gb = (w < 2) ? ag : bg;
    u16* lb = (w == 0) ? &A0[0][0] : (w == 1) ? &A1[0][0]
            : (w == 2) ? &B0[0][0] : &B1[0][0];
    const int rbase = (w < 2) ? r0 : c0;
    const int colofs = (w & 1) * 32;
    const u16* gsrc0 = gb + (size_t)(rbase + (lane >> 2)) * DM + colofs + (lane & 3) * 8;

    const int wr = (w >> 1) * 64, wc = (w & 1) * 64;

    f32x4 acc[4][4];
#pragma unroll
    for (int i = 0; i < 4; ++i)
#pragma unroll
        for (int j = 0; j < 4; ++j) acc[i][j] = (f32x4)0.f;

    for (int ks = 0; ks < DM; ks += 64) {
        __syncthreads();
#pragma unroll
        for (int i = 0; i < 8; ++i)
            async16(gsrc0 + (size_t)i * 16 * DM + ks, lb + i * 512);
        __syncthreads();

#pragma unroll
        for (int kk = 0; kk < 2; ++kk) {
            const u16(*Ak)[32] = kk ? A1 : A0;
            const u16(*Bk)[32] = kk ? B1 : B0;
            bf16x8 ah[4], bh[4];
#pragma unroll
            for (int rt = 0; rt < 4; ++rt)
                ah[rt] = *(const bf16x8*)&Ak[wr + rt * 16 + lc][lg * 8];
#pragma unroll
            for (int jt = 0; jt < 4; ++jt)
                bh[jt] = *(const bf16x8*)&Bk[wc + jt * 16 + lc][lg * 8];
#pragma unroll
            for (int jt = 0; jt < 4; ++jt)
#pragma unroll
                for (int rt = 0; rt < 4; ++rt)
                    acc[rt][jt] = MFMA(ah[rt], bh[jt], acc[rt][jt], 0, 0, 0);
        }
    }

#pragma unroll
    for (int rt = 0; rt < 4; ++rt)
#pragma unroll
        for (int jt = 0; jt < 4; ++jt)
#pragma unroll
            for (int r = 0; r < 4; ++r) {
                int row = r0 + wr + rt * 16 + lg * 4 + r;
                int col = c0 + wc + jt * 16 + lc;
                int h = col >> 6, d = col & 63, n = row >> 11, s = row & 2047;
                if (z == 0) {
                    float v = acc[rt][jt][r] + bias[col] * QSCALE;
                    size_t idx = ((size_t)((h << 1) | n) * SEQ + s) * HD + d;
                    qh[idx] = bf16_rne(v);
                } else if (z == 1) {
                    float v = acc[rt][jt][r] + bias[col];
                    size_t idx = ((size_t)((h << 1) | n) * SEQ + s) * HD + d;
                    kh[idx] = bf16_rne(v);
                } else {
                    float v = acc[rt][jt][r] + bias[col];
                    size_t idx = ((size_t)((h << 1) | n) * HD + d) * SEQ + s;
                    vth[idx] = bf16_rne(v);
                }
            }
}

// ---------------------------------------------------------------------------
// Final projection GEMM, 3-term split (unchanged — output-facing precision).
// ---------------------------------------------------------------------------
__global__ __launch_bounds__(256, 2) void gemm_proj(
    const u16* __restrict__ yh, const u16* __restrict__ yl,
    const u16* __restrict__ woh, const u16* __restrict__ wol,
    const float* __restrict__ bo, float* __restrict__ outf)
{
    __shared__ u16 Ah[128][32], Al[128][32], Bh[128][32], Bl[128][32];

    const int tid = threadIdx.x, lane = tid & 63, w = tid >> 6;
    const int lg = lane >> 4, lc = lane & 15;

    const int id = blockIdx.x + 8 * blockIdx.y;
    const int swz = (id & 7) * 32 + (id >> 3);
    const int c0 = (swz & 7) * 128, r0 = (swz >> 3) * 128;

    const u16* gb = (w == 0) ? yh : (w == 1) ? yl : (w == 2) ? woh : wol;
    u16* lb = (w == 0) ? &Ah[0][0] : (w == 1) ? &Al[0][0] : (w == 2) ? &Bh[0][0] : &Bl[0][0];
    const int rbase = (w < 2) ? r0 : c0;
    const u16* gsrc0 = gb + (size_t)(rbase + (lane >> 2)) * DM + (lane & 3) * 8;

    const int wr = (w >> 1) * 64, wc = (w & 1) * 64;

    f32x4 acc[4][4];
#pragma unroll
    for (int i = 0; i < 4; ++i)
#pragma unroll
        for (int j = 0; j < 4; ++j) acc[i][j] = (f32x4)0.f;

    for (int ks = 0; ks < DM; ks += 32) {
        __syncthreads();
#pragma unroll
        for (int i = 0; i < 8; ++i)
            async16(gsrc0 + (size_t)i * 16 * DM + ks, lb + i * 512);
        __syncthreads();

        bf16x8 ah[4], al[4];
#pragma unroll
        for (int rt = 0; rt < 4; ++rt) {
            ah[rt] = *(const bf16x8*)&Ah[wr + rt * 16 + lc][lg * 8];
            al[rt] = *(const bf16x8*)&Al[wr + rt * 16 + lc][lg * 8];
        }
#pragma unroll
        for (int jt = 0; jt < 4; ++jt) {
            bf16x8 bh2 = *(const bf16x8*)&Bh[wc + jt * 16 + lc][lg * 8];
            bf16x8 bl2 = *(const bf16x8*)&Bl[wc + jt * 16 + lc][lg * 8];
#pragma unroll
            for (int rt = 0; rt < 4; ++rt) {
                acc[rt][jt] = MFMA(ah[rt], bh2, acc[rt][jt], 0, 0, 0);
                acc[rt][jt] = MFMA(ah[rt], bl2, acc[rt][jt], 0, 0, 0);
                acc[rt][jt] = MFMA(al[rt], bh2, acc[rt][jt], 0, 0, 0);
            }
        }
    }

#pragma unroll
    for (int rt = 0; rt < 4; ++rt)
#pragma unroll
        for (int jt = 0; jt < 4; ++jt)
#pragma unroll
            for (int r = 0; r < 4; ++r) {
                int row = r0 + wr + rt * 16 + lg * 4 + r;
                int col = c0 + wc + jt * 16 + lc;
                outf[(size_t)row * DM + col] = acc[rt][jt][r] + bo[col];
            }
}

// ---------------------------------------------------------------------------
// Flash attention v5 (recovery): 1-term QK^T (q,k plain bf16) + ROUND-8
// PROVEN defer-max online softmax + explicit lgkmcnt(0)+sched_barrier fence
// between the Pb ds_writes and ds_reads (rule-18 reorder guard — the round-9
// failure class). Staging/swizzle/occupancy structure identical to round 8.
// ---------------------------------------------------------------------------
__global__ __launch_bounds__(256, 4) void attn_k(
    const u16* __restrict__ qh, const u16* __restrict__ kh,
    const u16* __restrict__ vth,
    u16* __restrict__ yh, u16* __restrict__ yl)
{
    __shared__ u16 Ks[2][64][64], Vs[2][64][64];
    __shared__ u16 Pb[4][16][64];

    const int tid = threadIdx.x, lane = tid & 63, w = tid >> 6;
    const int lg = lane >> 4, lc = lane & 15;

    // bijective XCD-chunk swizzle over 1024 blocks (1024 % 8 == 0)
    const int id = blockIdx.x + 32 * blockIdx.y;
    const int widx = (id & 7) * 128 + (id >> 3);
    const int hn = widx >> 5;
    const int qb0 = (widx & 31) * 64;

    const size_t qkbase = (size_t)hn * SEQ * HD;
    const size_t vbase = (size_t)hn * HD * SEQ;

    const int srow = lane >> 3;                       // row within chunk
    const int sg = (lane & 7) ^ (srow & 7);           // pre-swizzled source granule

#define STAGE_KV(buf, kt0)                                                   \
    {                                                                        \
        _Pragma("unroll")                                                    \
        for (int cc = 0; cc < 2; ++cc) {                                     \
            const int c = w * 2 + cc;                                        \
            const int r = c * 8 + srow;                                      \
            async16(kh + qkbase + (size_t)((kt0) + r) * HD + sg * 8,         \
                    &Ks[buf][0][0] + c * 512);                               \
            async16(vth + vbase + (size_t)r * SEQ + (kt0) + sg * 8,          \
                    &Vs[buf][0][0] + c * 512);                               \
        }                                                                    \
    }

    // Q fragments (plain bf16) — B-operand; 16 q-rows per wave
    bf16x8 qf[2];
#pragma unroll
    for (int kc = 0; kc < 2; ++kc) {
        size_t off = qkbase + (size_t)(qb0 + w * 16 + lc) * HD + kc * 32 + lg * 8;
        qf[kc] = *(const bf16x8*)(qh + off);
    }

    // O^T accumulator [dt]: row = d = dt*16+lg*4+r, col = q = lc
    f32x4 ot[4];
#pragma unroll
    for (int j = 0; j < 4; ++j) ot[j] = (f32x4)0.f;
    float m_ = -3e38f, s_ = 0.f;

    STAGE_KV(0, 0);
    asm volatile("s_waitcnt vmcnt(0)" ::: "memory");
    __syncthreads();

    int cur = 0;
    for (int t = 0; t < SEQ / 64; ++t) {
        if (t < SEQ / 64 - 1) STAGE_KV(cur ^ 1, (t + 1) * 64);

        // ---- S^T = K·Q^T (1-term): row=l, col=q=lc ----
        f32x4 st[4];
#pragma unroll
        for (int j = 0; j < 4; ++j) st[j] = (f32x4)0.f;
        __builtin_amdgcn_s_setprio(1);
#pragma unroll
        for (int jt = 0; jt < 4; ++jt)
#pragma unroll
            for (int kc = 0; kc < 2; ++kc) {
                bf16x8 k8 = *(const bf16x8*)
                    &Ks[cur][jt * 16 + lc][(((kc << 2) | lg) ^ (lc & 7)) * 8];
                st[jt] = MFMA(k8, qf[kc], st[jt], 0, 0, 0);
            }
        __builtin_amdgcn_s_setprio(0);

        // ---- online softmax with defer-max (round-8 proven) ----
        {
            float t0 = fmaxf(fmaxf(st[0][0], st[0][1]), fmaxf(st[0][2], st[0][3]));
            float t1 = fmaxf(fmaxf(st[1][0], st[1][1]), fmaxf(st[1][2], st[1][3]));
            float t2 = fmaxf(fmaxf(st[2][0], st[2][1]), fmaxf(st[2][2], st[2][3]));
            float t3 = fmaxf(fmaxf(st[3][0], st[3][1]), fmaxf(st[3][2], st[3][3]));
            float tm = fmaxf(fmaxf(t0, t1), fmaxf(t2, t3));
            tm = fmaxf(tm, __shfl_xor(tm, 16));
            tm = fmaxf(tm, __shfl_xor(tm, 32));
            if (__any(tm - m_ > 8.0f)) {
                float mnew = fmaxf(m_, tm);
                float resc = exp2_fast(m_ - mnew);
                m_ = mnew;
                s_ *= resc;
#pragma unroll
                for (int dt = 0; dt < 4; ++dt) {
                    ot[dt][0] *= resc; ot[dt][1] *= resc;
                    ot[dt][2] *= resc; ot[dt][3] *= resc;
                }
            }
#pragma unroll
            for (int jt = 0; jt < 4; ++jt) {
                float p0 = exp2_fast(st[jt][0] - m_);
                float p1 = exp2_fast(st[jt][1] - m_);
                float p2 = exp2_fast(st[jt][2] - m_);
                float p3 = exp2_fast(st[jt][3] - m_);
                s_ += (p0 + p1) + (p2 + p3);
                u32x2 pk = {cvt_pk_bf16(p0, p1), cvt_pk_bf16(p2, p3)};
                // P[q=lc][l = jt*16+lg*4 ..+3], XOR-swizzled
                *(u32x2*)&Pb[w][lc][(jt * 16 + lg * 4) ^ ((lc & 7) << 3)] = pk;
            }
        }

        // fence: Pb ds_writes must complete & stay ordered before ds_reads
        // (rule-18: compiler may reorder differently-typed LDS accesses)
        asm volatile("s_waitcnt lgkmcnt(0)" ::: "memory");
        __builtin_amdgcn_sched_barrier(0);

        // ---- O^T += V^T · P^T ----
        bf16x8 pb[2];
#pragma unroll
        for (int jc = 0; jc < 2; ++jc)
            pb[jc] = *(const bf16x8*)
                &Pb[w][lc][(jc * 32 + lg * 8) ^ ((lc & 7) << 3)];
        __builtin_amdgcn_s_setprio(1);
#pragma unroll
        for (int dt = 0; dt < 4; ++dt)
#pragma unroll
            for (int jc = 0; jc < 2; ++jc) {
                bf16x8 v8 = *(const bf16x8*)
                    &Vs[cur][dt * 16 + lc][(((jc << 2) | lg) ^ (lc & 7)) * 8];
                ot[dt] = MFMA(v8, pb[jc], ot[dt], 0, 0, 0);
            }
        __builtin_amdgcn_s_setprio(0);

        asm volatile("s_waitcnt vmcnt(0)" ::: "memory");
        __syncthreads();
        cur ^= 1;
    }

    // ---- epilogue: reduce sum over lg groups, normalize, write y ----
    const int h = hn >> 1, n = hn & 1;
    {
        float v = s_;
        v += __shfl_xor(v, 16);
        v += __shfl_xor(v, 32);
        s_ = 1.f / v;
    }
    const int qrow = qb0 + w * 16 + lc;
    size_t rowoff = (size_t)(n * SEQ + qrow) * DM + h * HD;
#pragma unroll
    for (int dt = 0; dt < 4; ++dt) {
        u16x4 hv, lv;
#pragma unroll
        for (int r = 0; r < 4; ++r) {
            float y = ot[dt][r] * s_;
            u16 hh, ll; split2(y, hh, ll);
            hv[r] = hh; lv[r] = ll;
        }
        size_t idx = rowoff + dt * 16 + lg * 4;
        *(u16x4*)(yh + idx) = hv;
        *(u16x4*)(yl + idx) = lv;
    }
#undef STAGE_KV
}

// ---------------------------------------------------------------------------
extern "C" void kernel_launch(void* const* d_in, const int* in_sizes, int n_in,
                              void* d_out, int out_size, void* d_ws, size_t ws_size,
                              hipStream_t stream)
{
    const float* query = (const float*)d_in[0];
    const float* key_  = (const float*)d_in[1];
    const float* value = (const float*)d_in[2];
    const float* Wq = (const float*)d_in[3];
    const float* bq = (const float*)d_in[4];
    const float* Wk = (const float*)d_in[5];
    const float* bk = (const float*)d_in[6];
    const float* Wv = (const float*)d_in[7];
    const float* bv = (const float*)d_in[8];
    const float* Wo = (const float*)d_in[9];
    const float* bo = (const float*)d_in[10];
    float* out = (float*)d_out;

    char* p = (char*)d_ws;
    u16* wh  = (u16*)(p);
    u16* wl  = (u16*)(p + 8388608ull);
    u16* qh  = (u16*)(p + 16777216ull);
    u16* kh  = (u16*)(p + 33554432ull);
    u16* vth = (u16*)(p + 50331648ull);
    u16* xh  = (u16*)(p + 67108864ull);
    u16* yh  = (u16*)(p + 67108864ull);
    u16* yl  = (u16*)(p + 75497472ull);

    presplit<<<dim3(256, 7), 256, 0, stream>>>(
        query, key_, value, Wq, Wk, Wv, Wo, xh, wh, wl);

    gemm_qkv<<<dim3(8, 32, 3), 256, 0, stream>>>(
        xh, wh, bq, bk, bv, qh, kh, vth);

    attn_k<<<dim3(32, 32), 256, 0, stream>>>(qh, kh, vth, yh, yl);

    gemm_proj<<<dim3(8, 32), 256, 0, stream>>>(
        yh, yl, wh + 3145728ull, wl + 3145728ull, bo, out);
}